// Round 20
// baseline (506.589 us; speedup 1.0000x reference)
//
#include <hip/hip_runtime.h>
#include <hip/hip_bf16.h>
#include <stdint.h>

#define N_ROWS 512
#define D_DIM  512
#define C_CLS  100000

#define SCALE_F    64.0f
#define EPS_F      1e-7f
#define COS_M_F    0.8775825618903728f
#define SIN_M_F    0.4794255386042030f
#define THRESH_F  -0.8775825618903728f
#define MM_F       0.2397127693021015f
#define FIXMAX_F   65.0f        // fixed softmax max: all logits <= ~64.7 < 65

#define NC  64          // classes per block
#define NG2 1564        // ceil(100000/64) -> 1564*64 = 100096

// ---- ws layout (bytes) ----
#define XN8_OFF    0                          // fp8 [512][512] = 256 KB
#define TL_OFF     (XN8_OFF + 512*512)        // f32 [512]
#define CTM_OFF    (TL_OFF + 2048)            // f32 [512]
#define FTL_OFF    (CTM_OFF + 2048)           // f32 [512]
#define TNEW_OFF   (FTL_OFF + 2048)           // f32 [1] (padded)
#define PSUM_OFF   (TNEW_OFF + 256)           // f32 [512][NG2] = 3.2 MB
#define LOSSI_OFF  (PSUM_OFF + 512*NG2*4)     // f32 [512]

typedef __attribute__((ext_vector_type(4))) float f32x4;

#define GLOAD_LDS16(gp, lp) \
    __builtin_amdgcn_global_load_lds((const __attribute__((address_space(1))) void*)(gp), \
                                     (__attribute__((address_space(3))) void*)(lp), 16, 0, 0)

#if defined(__has_builtin)
#if __has_builtin(__builtin_amdgcn_cvt_pk_fp8_f32)
#define HAVE_CVT_FP8 1
#endif
#endif

// manual OCP e4m3fn fallback (round-to-nearest; saturating; no inf)
__device__ inline unsigned char f2e4m3(float f) {
    union { float f; unsigned u; } a; a.f = f;
    unsigned s = (a.u >> 24) & 0x80u;
    float af = fabsf(f);
    if (af < 0.015625f) {
        int q = (int)(af * 512.0f + 0.5f);
        return (unsigned char)(s | (unsigned)q);
    }
    unsigned x = a.u & 0x7FFFFFFFu;
    unsigned r = x + 0x000FFFFFu + ((x >> 20) & 1u);
    int ec = (int)(r >> 23) - 127 + 7;
    unsigned m = (r >> 20) & 7u;
    if (ec > 15 || (ec == 15 && m == 7u)) return (unsigned char)(s | 0x7Eu);
    return (unsigned char)(s | ((unsigned)ec << 3) | m);
}

__device__ inline unsigned pack4_fp8(float f0, float f1, float f2, float f3) {
#ifdef HAVE_CVT_FP8
    int q = __builtin_amdgcn_cvt_pk_fp8_f32(f0, f1, 0, false);
    q     = __builtin_amdgcn_cvt_pk_fp8_f32(f2, f3, q, true);
    return (unsigned)q;
#else
    union { unsigned char b[4]; unsigned u; } u;
    u.b[0]=f2e4m3(f0); u.b[1]=f2e4m3(f1); u.b[2]=f2e4m3(f2); u.b[3]=f2e4m3(f3);
    return u.u;
#endif
}

__device__ inline float wave_sum64(float v) {
    #pragma unroll
    for (int m = 1; m < 64; m <<= 1) v += __shfl_xor(v, m);
    return v;
}

// K1: FUSED prep: x row norm + fp8 pack + target logit/margins (x read once).
// grid 512 x 64
__global__ void k_prep(const float* __restrict__ x, const float* __restrict__ w,
                       const int* __restrict__ target,
                       unsigned char* __restrict__ xn8,
                       float* __restrict__ tl, float* __restrict__ ctm,
                       float* __restrict__ ftl) {
    int row = blockIdx.x;
    int lane = threadIdx.x;
    const float* xr = x + row * D_DIM + lane * 8;
    float4 v0 = *(const float4*)(xr);
    float4 v1 = *(const float4*)(xr + 4);
    float sx = v0.x*v0.x + v0.y*v0.y + v0.z*v0.z + v0.w*v0.w
             + v1.x*v1.x + v1.y*v1.y + v1.z*v1.z + v1.w*v1.w;
    sx = wave_sum64(sx);
    float nrm = sqrtf(sx);
    float inv = 1.0f / nrm;
    uint2 q8;
    q8.x = pack4_fp8(v0.x*inv, v0.y*inv, v0.z*inv, v0.w*inv);
    q8.y = pack4_fp8(v1.x*inv, v1.y*inv, v1.z*inv, v1.w*inv);
    *(uint2*)(xn8 + row * D_DIM + lane * 8) = q8;

    int tgt = target[row];
    const float* wr = w + (size_t)tgt * D_DIM + lane * 8;
    float4 b0 = *(const float4*)(wr), b1 = *(const float4*)(wr + 4);
    float s = v0.x*b0.x + v0.y*b0.y + v0.z*b0.z + v0.w*b0.w
            + v1.x*b1.x + v1.y*b1.y + v1.z*b1.z + v1.w*b1.w;
    float q = b0.x*b0.x + b0.y*b0.y + b0.z*b0.z + b0.w*b0.w
            + b1.x*b1.x + b1.y*b1.y + b1.z*b1.z + b1.w*b1.w;
    s = wave_sum64(s);
    q = wave_sum64(q);
    if (lane == 0) {
        float c = s / (nrm * sqrtf(q));
        c = fminf(fmaxf(c, -1.0f + EPS_F), 1.0f - EPS_F);
        float sn = sqrtf(fmaxf(1.0f - c * c, 0.0f));
        float cm = c * COS_M_F - sn * SIN_M_F;
        tl[row]  = c;
        ctm[row] = cm;
        ftl[row] = (c > THRESH_F) ? cm : (c - MM_F);
    }
}

// K1b: t_new = mean(tl)*0.01 + 0.99*t.  1 x 512
__global__ void k_tnew(const float* __restrict__ tl, const float* __restrict__ t,
                       float* __restrict__ tnew) {
    __shared__ float s[512];
    int tid = threadIdx.x;
    s[tid] = tl[tid];
    __syncthreads();
    for (int off = 256; off > 0; off >>= 1) {
        if (tid < off) s[tid] += s[tid + off];
        __syncthreads();
    }
    if (tid == 0) tnew[0] = (s[0] / 512.0f) * 0.01f + 0.99f * t[0];
}

// ---------------------------------------------------------------------------
// K2: FUSED single-pass kernel (r12/r19 champion).  ONLY change this round:
//  __launch_bounds__(512, 6) -> allow 3 resident blocks/CU (LDS 43.5 KB x 3
//  = 130.6 < 160 KB; VGPR cap 85 >= our 60).  Cross-block overlap is the one
//  agent that can hide a whole-block barrier drain.
// grid 1564 x 512
// ---------------------------------------------------------------------------
__global__ __launch_bounds__(512, 6) void k_fused(
        const unsigned char* __restrict__ xn8,    // fp8 [512][512], normalized
        const float* __restrict__ w,              // f32 [100000][512] RAW
        const int* __restrict__ target,
        const float* __restrict__ ctm,
        const float* __restrict__ ftl,
        const float* __restrict__ tnew,
        float* __restrict__ psum) {
    __shared__ unsigned char As[2][512 * 32];     // 2 x 16 KB
    __shared__ unsigned char Bs[2][64 * 32];      // 2 x 2 KB
    __shared__ float invS[64];
    __shared__ int   tgt_s[512];
    __shared__ float ctm_s[512];
    __shared__ float ftl_s[512];

    int bx = blockIdx.x;
    int cb = bx * NC;                  // first class of this block
    int tid = threadIdx.x;
    int lane = tid & 63, wid = tid >> 6;
    int fr = lane & 15, rgrp = lane >> 4;
    int wrow = wid * 64;               // wave's first A-row

    tgt_s[tid] = target[tid];
    ctm_s[tid] = ctm[tid];
    ftl_s[tid] = ftl[tid];

    // ---- B staging assignment: thread -> (class-row, 4-f32 slot) ----
    int brow  = tid >> 3;              // 0..63
    int bslot = tid & 7;               // 0..7
    int bclass = cb + brow;
    bool brvalid = (bclass < C_CLS);
    const float* bsrc = w + (size_t)(brvalid ? bclass : 0) * D_DIM + bslot * 4;

    float sumsq = 0.0f;

    // stage A slice kk into As[buf] (2 x 8 KB global_load_lds, linear)
    #define STAGE_A(kk, buf)                                                  \
        do {                                                                  \
            _Pragma("unroll")                                                 \
            for (int c = 0; c < 2; ++c) {                                     \
                int lo = c * 8192 + wid * 1024;      /* wave-uniform */       \
                int o  = lo + lane * 16;                                      \
                int row = o >> 5, b = o & 31;                                 \
                GLOAD_LDS16(xn8 + (size_t)row * 512 + (kk) * 32 + b,          \
                            (char*)As[buf] + lo);                             \
            }                                                                 \
        } while (0)

    // stage B slice kk into Bs[buf]: load 4 f32, sumsq, cvt fp8, ds_write 4B
    #define STAGE_B(kk, buf)                                                  \
        do {                                                                  \
            float4 v_ = *(const float4*)(bsrc + (kk) * 32);                   \
            sumsq += v_.x*v_.x + v_.y*v_.y + v_.z*v_.z + v_.w*v_.w;           \
            *(unsigned*)(&Bs[buf][brow * 32 + bslot * 4]) =                   \
                pack4_fp8(v_.x, v_.y, v_.z, v_.w);                            \
        } while (0)

    // prologue: stage kk=0
    STAGE_A(0, 0);
    STAGE_B(0, 0);
    __syncthreads();

    float tn = tnew[0];

    f32x4 acc[4][4];                   // [m][j]
    #pragma unroll
    for (int m = 0; m < 4; m++)
        #pragma unroll
        for (int j = 0; j < 4; j++)
            acc[m][j] = (f32x4){0.f, 0.f, 0.f, 0.f};

    union LL { uint2 u; long long ll; };

    for (int kk = 0; kk < 16; ++kk) {
        int cur = kk & 1;
        if (kk < 15) {
            STAGE_A(kk + 1, cur ^ 1);
            STAGE_B(kk + 1, cur ^ 1);
        }
        // frags from current buffers
        uint2 af[4], bf[4];
        #pragma unroll
        for (int m = 0; m < 4; m++)
            af[m] = *(const uint2*)(&As[cur][(wrow + m * 16 + fr) * 32 + rgrp * 8]);
        #pragma unroll
        for (int j = 0; j < 4; j++)
            bf[j] = *(const uint2*)(&Bs[cur][(j * 16 + fr) * 32 + rgrp * 8]);
        __builtin_amdgcn_s_setprio(1);
        #pragma unroll
        for (int m = 0; m < 4; m++)
            #pragma unroll
            for (int j = 0; j < 4; j++) {
                LL a, b;
                a.u = af[m];
                b.u = bf[j];
                acc[m][j] = __builtin_amdgcn_mfma_f32_16x16x32_fp8_fp8(
                                a.ll, b.ll, acc[m][j], 0, 0, 0);
            }
        __builtin_amdgcn_s_setprio(0);
        __syncthreads();               // next-slice staged; buffers handoff
    }
    #undef STAGE_A
    #undef STAGE_B

    // ---- combine sumsq (8 threads per class row) -> invS ----
    float s2 = sumsq;
    s2 += __shfl_xor(s2, 1);
    s2 += __shfl_xor(s2, 2);
    s2 += __shfl_xor(s2, 4);
    if (bslot == 0) invS[brow] = rsqrtf(s2);
    __syncthreads();

    // ---- epilogue: fixed-max transform + exp + row sum ----
    // C/D layout: col = cb + j*16 + fr, row = wrow + m*16 + rgrp*4 + reg.
    float inv[4];
    bool cvalid[4];
    #pragma unroll
    for (int j = 0; j < 4; j++) {
        inv[j] = invS[j * 16 + fr];
        cvalid[j] = (cb + j * 16 + fr) < C_CLS;
    }
    #pragma unroll
    for (int m = 0; m < 4; m++) {
        #pragma unroll
        for (int reg = 0; reg < 4; reg++) {
            int rl = wrow + m * 16 + rgrp * 4 + reg;
            int tr = tgt_s[rl];
            float cm = ctm_s[rl];
            float ft = ftl_s[rl];
            float sm = 0.0f;
            #pragma unroll
            for (int j = 0; j < 4; j++) {
                int col = cb + j * 16 + fr;
                float c = acc[m][j][reg] * inv[j];
                c = fminf(fmaxf(c, -1.0f + EPS_F), 1.0f - EPS_F);
                float v = (c > cm) ? c * (tn + c) : c;
                v *= SCALE_F;
                v = (col == tr) ? ft * SCALE_F : v;
                v = cvalid[j] ? v : -3.0e38f;   // exp -> 0
                sm += __expf(v - FIXMAX_F);
            }
            #pragma unroll
            for (int msk = 1; msk < 16; msk <<= 1) sm += __shfl_xor(sm, msk);
            if (fr == 0) psum[(size_t)rl * NG2 + bx] = sm;
        }
    }
}

// K3: per-row sum over NG2 partials (fixed max) -> loss_i.  grid 512 x 256
__global__ void k_rowlse_fix(const float* __restrict__ psum,
                             const float* __restrict__ ftl,
                             float* __restrict__ lossi) {
    int row = blockIdx.x, tid = threadIdx.x;
    float S = 0.0f;
    for (int nb = tid; nb < NG2; nb += 256) S += psum[(size_t)row * NG2 + nb];
    __shared__ float sS[256];
    sS[tid] = S;
    __syncthreads();
    for (int off = 128; off > 0; off >>= 1) {
        if (tid < off) sS[tid] += sS[tid + off];
        __syncthreads();
    }
    if (tid == 0) lossi[row] = logf(sS[0]) + FIXMAX_F - SCALE_F * ftl[row];
}

// K4: loss = mean(loss_i).  1 x 512
__global__ void k_final(const float* __restrict__ lossi, float* __restrict__ out) {
    __shared__ float s[512];
    int tid = threadIdx.x;
    s[tid] = lossi[tid];
    __syncthreads();
    for (int off = 256; off > 0; off >>= 1) {
        if (tid < off) s[tid] += s[tid + off];
        __syncthreads();
    }
    if (tid == 0) out[0] = s[0] / 512.0f;
}

extern "C" void kernel_launch(void* const* d_in, const int* in_sizes, int n_in,
                              void* d_out, int out_size, void* d_ws, size_t ws_size,
                              hipStream_t stream) {
    const float* x      = (const float*)d_in[0];
    const float* w      = (const float*)d_in[1];
    const float* t      = (const float*)d_in[2];
    const int*   target = (const int*)d_in[3];

    char* ws = (char*)d_ws;
    unsigned char* xn8  = (unsigned char*)(ws + XN8_OFF);
    float* tl    = (float*)(ws + TL_OFF);
    float* ctm   = (float*)(ws + CTM_OFF);
    float* ftl   = (float*)(ws + FTL_OFF);
    float* tnew  = (float*)(ws + TNEW_OFF);
    float* psum  = (float*)(ws + PSUM_OFF);
    float* lossi = (float*)(ws + LOSSI_OFF);
    float* out   = (float*)d_out;

    k_prep<<<dim3(N_ROWS), dim3(64), 0, stream>>>(x, w, target, xn8, tl, ctm, ftl);
    k_tnew<<<dim3(1), dim3(512), 0, stream>>>(tl, t, tnew);
    k_fused<<<dim3(NG2), dim3(512), 0, stream>>>(xn8, w, target, ctm, ftl, tnew, psum);
    k_rowlse_fix<<<dim3(N_ROWS), dim3(256), 0, stream>>>(psum, ftl, lossi);
    k_final<<<dim3(1), dim3(512), 0, stream>>>(lossi, out);
}

// Round 21
// 119.862 us; speedup vs baseline: 4.2264x; 4.2264x over previous
//
#include <hip/hip_runtime.h>
#include <hip/hip_bf16.h>
#include <stdint.h>

#define N_ROWS 512
#define D_DIM  512
#define C_CLS  100000

#define SCALE_F    64.0f
#define EPS_F      1e-7f
#define COS_M_F    0.8775825618903728f
#define SIN_M_F    0.4794255386042030f
#define THRESH_F  -0.8775825618903728f
#define MM_F       0.2397127693021015f
#define FIXMAX_F   65.0f        // fixed softmax max: all logits <= ~64.7 < 65

#define NC  64          // classes per block
#define NG2 1564        // ceil(100000/64) -> 1564*64 = 100096

// ---- ws layout (bytes) ----
#define XN8_OFF    0                          // fp8 [512][512] = 256 KB
#define TL_OFF     (XN8_OFF + 512*512)        // f32 [512]
#define CTM_OFF    (TL_OFF + 2048)            // f32 [512]
#define FTL_OFF    (CTM_OFF + 2048)           // f32 [512]
#define TNEW_OFF   (FTL_OFF + 2048)           // f32 [1] (padded)
#define PSUM_OFF   (TNEW_OFF + 256)           // f32 [512][NG2] = 3.2 MB
#define LOSSI_OFF  (PSUM_OFF + 512*NG2*4)     // f32 [512]

typedef __attribute__((ext_vector_type(4))) float f32x4;

#define GLOAD_LDS16(gp, lp) \
    __builtin_amdgcn_global_load_lds((const __attribute__((address_space(1))) void*)(gp), \
                                     (__attribute__((address_space(3))) void*)(lp), 16, 0, 0)

#if defined(__has_builtin)
#if __has_builtin(__builtin_amdgcn_cvt_pk_fp8_f32)
#define HAVE_CVT_FP8 1
#endif
#endif

// manual OCP e4m3fn fallback (round-to-nearest; saturating; no inf)
__device__ inline unsigned char f2e4m3(float f) {
    union { float f; unsigned u; } a; a.f = f;
    unsigned s = (a.u >> 24) & 0x80u;
    float af = fabsf(f);
    if (af < 0.015625f) {
        int q = (int)(af * 512.0f + 0.5f);
        return (unsigned char)(s | (unsigned)q);
    }
    unsigned x = a.u & 0x7FFFFFFFu;
    unsigned r = x + 0x000FFFFFu + ((x >> 20) & 1u);
    int ec = (int)(r >> 23) - 127 + 7;
    unsigned m = (r >> 20) & 7u;
    if (ec > 15 || (ec == 15 && m == 7u)) return (unsigned char)(s | 0x7Eu);
    return (unsigned char)(s | ((unsigned)ec << 3) | m);
}

__device__ inline unsigned pack4_fp8(float f0, float f1, float f2, float f3) {
#ifdef HAVE_CVT_FP8
    int q = __builtin_amdgcn_cvt_pk_fp8_f32(f0, f1, 0, false);
    q     = __builtin_amdgcn_cvt_pk_fp8_f32(f2, f3, q, true);
    return (unsigned)q;
#else
    union { unsigned char b[4]; unsigned u; } u;
    u.b[0]=f2e4m3(f0); u.b[1]=f2e4m3(f1); u.b[2]=f2e4m3(f2); u.b[3]=f2e4m3(f3);
    return u.u;
#endif
}

__device__ inline float wave_sum64(float v) {
    #pragma unroll
    for (int m = 1; m < 64; m <<= 1) v += __shfl_xor(v, m);
    return v;
}

// K1: FUSED prep: x row norm + fp8 pack + target logit/margins (x read once).
// grid 512 x 64
__global__ void k_prep(const float* __restrict__ x, const float* __restrict__ w,
                       const int* __restrict__ target,
                       unsigned char* __restrict__ xn8,
                       float* __restrict__ tl, float* __restrict__ ctm,
                       float* __restrict__ ftl) {
    int row = blockIdx.x;
    int lane = threadIdx.x;
    const float* xr = x + row * D_DIM + lane * 8;
    float4 v0 = *(const float4*)(xr);
    float4 v1 = *(const float4*)(xr + 4);
    float sx = v0.x*v0.x + v0.y*v0.y + v0.z*v0.z + v0.w*v0.w
             + v1.x*v1.x + v1.y*v1.y + v1.z*v1.z + v1.w*v1.w;
    sx = wave_sum64(sx);
    float nrm = sqrtf(sx);
    float inv = 1.0f / nrm;
    uint2 q8;
    q8.x = pack4_fp8(v0.x*inv, v0.y*inv, v0.z*inv, v0.w*inv);
    q8.y = pack4_fp8(v1.x*inv, v1.y*inv, v1.z*inv, v1.w*inv);
    *(uint2*)(xn8 + row * D_DIM + lane * 8) = q8;

    int tgt = target[row];
    const float* wr = w + (size_t)tgt * D_DIM + lane * 8;
    float4 b0 = *(const float4*)(wr), b1 = *(const float4*)(wr + 4);
    float s = v0.x*b0.x + v0.y*b0.y + v0.z*b0.z + v0.w*b0.w
            + v1.x*b1.x + v1.y*b1.y + v1.z*b1.z + v1.w*b1.w;
    float q = b0.x*b0.x + b0.y*b0.y + b0.z*b0.z + b0.w*b0.w
            + b1.x*b1.x + b1.y*b1.y + b1.z*b1.z + b1.w*b1.w;
    s = wave_sum64(s);
    q = wave_sum64(q);
    if (lane == 0) {
        float c = s / (nrm * sqrtf(q));
        c = fminf(fmaxf(c, -1.0f + EPS_F), 1.0f - EPS_F);
        float sn = sqrtf(fmaxf(1.0f - c * c, 0.0f));
        float cm = c * COS_M_F - sn * SIN_M_F;
        tl[row]  = c;
        ctm[row] = cm;
        ftl[row] = (c > THRESH_F) ? cm : (c - MM_F);
    }
}

// K1b: t_new = mean(tl)*0.01 + 0.99*t.  1 x 512
__global__ void k_tnew(const float* __restrict__ tl, const float* __restrict__ t,
                       float* __restrict__ tnew) {
    __shared__ float s[512];
    int tid = threadIdx.x;
    s[tid] = tl[tid];
    __syncthreads();
    for (int off = 256; off > 0; off >>= 1) {
        if (tid < off) s[tid] += s[tid + off];
        __syncthreads();
    }
    if (tid == 0) tnew[0] = (s[0] / 512.0f) * 0.01f + 0.99f * t[0];
}

// ---------------------------------------------------------------------------
// K2: FUSED single-pass kernel (r12/r19 champion, byte-identical).
//  Each block: ALL 512 rows x 64 classes.
//  - w (f32) read exactly ONCE chip-wide: per step, 64 rows x 128 B
//    coalesced; each thread loads 4 f32, accumulates ||w||^2 inline,
//    converts to fp8 ONCE, ds_writes 4 B into the B double-buffer.
//  - A (xn8, 256 KB, L2-resident) streams per-step via global_load_lds dbuf.
//  - per wave per step: 16 MFMA (fp8 16x16x32); one barrier per step.
//  - 1/||w|| applied as a column scale in the epilogue (invS exchange).
//  - fixed softmax max (=65): exp+sum only; per-row partial -> psum[row][bx].
//  NOTE: (512,4) is the measured optimum; (512,6) forces VGPR<=85, allocator
//  drops to 40 and SPILLS acc (r20: 940 MB scratch writes, 4.4x slower).
// grid 1564 x 512
// ---------------------------------------------------------------------------
__global__ __launch_bounds__(512, 4) void k_fused(
        const unsigned char* __restrict__ xn8,    // fp8 [512][512], normalized
        const float* __restrict__ w,              // f32 [100000][512] RAW
        const int* __restrict__ target,
        const float* __restrict__ ctm,
        const float* __restrict__ ftl,
        const float* __restrict__ tnew,
        float* __restrict__ psum) {
    __shared__ unsigned char As[2][512 * 32];     // 2 x 16 KB
    __shared__ unsigned char Bs[2][64 * 32];      // 2 x 2 KB
    __shared__ float invS[64];
    __shared__ int   tgt_s[512];
    __shared__ float ctm_s[512];
    __shared__ float ftl_s[512];

    int bx = blockIdx.x;
    int cb = bx * NC;                  // first class of this block
    int tid = threadIdx.x;
    int lane = tid & 63, wid = tid >> 6;
    int fr = lane & 15, rgrp = lane >> 4;
    int wrow = wid * 64;               // wave's first A-row

    tgt_s[tid] = target[tid];
    ctm_s[tid] = ctm[tid];
    ftl_s[tid] = ftl[tid];

    // ---- B staging assignment: thread -> (class-row, 4-f32 slot) ----
    int brow  = tid >> 3;              // 0..63
    int bslot = tid & 7;               // 0..7
    int bclass = cb + brow;
    bool brvalid = (bclass < C_CLS);
    const float* bsrc = w + (size_t)(brvalid ? bclass : 0) * D_DIM + bslot * 4;

    float sumsq = 0.0f;

    // stage A slice kk into As[buf] (2 x 8 KB global_load_lds, linear)
    #define STAGE_A(kk, buf)                                                  \
        do {                                                                  \
            _Pragma("unroll")                                                 \
            for (int c = 0; c < 2; ++c) {                                     \
                int lo = c * 8192 + wid * 1024;      /* wave-uniform */       \
                int o  = lo + lane * 16;                                      \
                int row = o >> 5, b = o & 31;                                 \
                GLOAD_LDS16(xn8 + (size_t)row * 512 + (kk) * 32 + b,          \
                            (char*)As[buf] + lo);                             \
            }                                                                 \
        } while (0)

    // stage B slice kk into Bs[buf]: load 4 f32, sumsq, cvt fp8, ds_write 4B
    #define STAGE_B(kk, buf)                                                  \
        do {                                                                  \
            float4 v_ = *(const float4*)(bsrc + (kk) * 32);                   \
            sumsq += v_.x*v_.x + v_.y*v_.y + v_.z*v_.z + v_.w*v_.w;           \
            *(unsigned*)(&Bs[buf][brow * 32 + bslot * 4]) =                   \
                pack4_fp8(v_.x, v_.y, v_.z, v_.w);                            \
        } while (0)

    // prologue: stage kk=0
    STAGE_A(0, 0);
    STAGE_B(0, 0);
    __syncthreads();

    float tn = tnew[0];

    f32x4 acc[4][4];                   // [m][j]
    #pragma unroll
    for (int m = 0; m < 4; m++)
        #pragma unroll
        for (int j = 0; j < 4; j++)
            acc[m][j] = (f32x4){0.f, 0.f, 0.f, 0.f};

    union LL { uint2 u; long long ll; };

    for (int kk = 0; kk < 16; ++kk) {
        int cur = kk & 1;
        if (kk < 15) {
            STAGE_A(kk + 1, cur ^ 1);
            STAGE_B(kk + 1, cur ^ 1);
        }
        // frags from current buffers
        uint2 af[4], bf[4];
        #pragma unroll
        for (int m = 0; m < 4; m++)
            af[m] = *(const uint2*)(&As[cur][(wrow + m * 16 + fr) * 32 + rgrp * 8]);
        #pragma unroll
        for (int j = 0; j < 4; j++)
            bf[j] = *(const uint2*)(&Bs[cur][(j * 16 + fr) * 32 + rgrp * 8]);
        __builtin_amdgcn_s_setprio(1);
        #pragma unroll
        for (int m = 0; m < 4; m++)
            #pragma unroll
            for (int j = 0; j < 4; j++) {
                LL a, b;
                a.u = af[m];
                b.u = bf[j];
                acc[m][j] = __builtin_amdgcn_mfma_f32_16x16x32_fp8_fp8(
                                a.ll, b.ll, acc[m][j], 0, 0, 0);
            }
        __builtin_amdgcn_s_setprio(0);
        __syncthreads();               // next-slice staged; buffers handoff
    }
    #undef STAGE_A
    #undef STAGE_B

    // ---- combine sumsq (8 threads per class row) -> invS ----
    float s2 = sumsq;
    s2 += __shfl_xor(s2, 1);
    s2 += __shfl_xor(s2, 2);
    s2 += __shfl_xor(s2, 4);
    if (bslot == 0) invS[brow] = rsqrtf(s2);
    __syncthreads();

    // ---- epilogue: fixed-max transform + exp + row sum ----
    // C/D layout: col = cb + j*16 + fr, row = wrow + m*16 + rgrp*4 + reg.
    float inv[4];
    bool cvalid[4];
    #pragma unroll
    for (int j = 0; j < 4; j++) {
        inv[j] = invS[j * 16 + fr];
        cvalid[j] = (cb + j * 16 + fr) < C_CLS;
    }
    #pragma unroll
    for (int m = 0; m < 4; m++) {
        #pragma unroll
        for (int reg = 0; reg < 4; reg++) {
            int rl = wrow + m * 16 + rgrp * 4 + reg;
            int tr = tgt_s[rl];
            float cm = ctm_s[rl];
            float ft = ftl_s[rl];
            float sm = 0.0f;
            #pragma unroll
            for (int j = 0; j < 4; j++) {
                int col = cb + j * 16 + fr;
                float c = acc[m][j][reg] * inv[j];
                c = fminf(fmaxf(c, -1.0f + EPS_F), 1.0f - EPS_F);
                float v = (c > cm) ? c * (tn + c) : c;
                v *= SCALE_F;
                v = (col == tr) ? ft * SCALE_F : v;
                v = cvalid[j] ? v : -3.0e38f;   // exp -> 0
                sm += __expf(v - FIXMAX_F);
            }
            #pragma unroll
            for (int msk = 1; msk < 16; msk <<= 1) sm += __shfl_xor(sm, msk);
            if (fr == 0) psum[(size_t)rl * NG2 + bx] = sm;
        }
    }
}

// K3: per-row sum over NG2 partials (fixed max) -> loss_i.  grid 512 x 256
__global__ void k_rowlse_fix(const float* __restrict__ psum,
                             const float* __restrict__ ftl,
                             float* __restrict__ lossi) {
    int row = blockIdx.x, tid = threadIdx.x;
    float S = 0.0f;
    for (int nb = tid; nb < NG2; nb += 256) S += psum[(size_t)row * NG2 + nb];
    __shared__ float sS[256];
    sS[tid] = S;
    __syncthreads();
    for (int off = 128; off > 0; off >>= 1) {
        if (tid < off) sS[tid] += sS[tid + off];
        __syncthreads();
    }
    if (tid == 0) lossi[row] = logf(sS[0]) + FIXMAX_F - SCALE_F * ftl[row];
}

// K4: loss = mean(loss_i).  1 x 512
__global__ void k_final(const float* __restrict__ lossi, float* __restrict__ out) {
    __shared__ float s[512];
    int tid = threadIdx.x;
    s[tid] = lossi[tid];
    __syncthreads();
    for (int off = 256; off > 0; off >>= 1) {
        if (tid < off) s[tid] += s[tid + off];
        __syncthreads();
    }
    if (tid == 0) out[0] = s[0] / 512.0f;
}

extern "C" void kernel_launch(void* const* d_in, const int* in_sizes, int n_in,
                              void* d_out, int out_size, void* d_ws, size_t ws_size,
                              hipStream_t stream) {
    const float* x      = (const float*)d_in[0];
    const float* w      = (const float*)d_in[1];
    const float* t      = (const float*)d_in[2];
    const int*   target = (const int*)d_in[3];

    char* ws = (char*)d_ws;
    unsigned char* xn8  = (unsigned char*)(ws + XN8_OFF);
    float* tl    = (float*)(ws + TL_OFF);
    float* ctm   = (float*)(ws + CTM_OFF);
    float* ftl   = (float*)(ws + FTL_OFF);
    float* tnew  = (float*)(ws + TNEW_OFF);
    float* psum  = (float*)(ws + PSUM_OFF);
    float* lossi = (float*)(ws + LOSSI_OFF);
    float* out   = (float*)d_out;

    k_prep<<<dim3(N_ROWS), dim3(64), 0, stream>>>(x, w, target, xn8, tl, ctm, ftl);
    k_tnew<<<dim3(1), dim3(512), 0, stream>>>(tl, t, tnew);
    k_fused<<<dim3(NG2), dim3(512), 0, stream>>>(xn8, w, target, ctm, ftl, tnew, psum);
    k_rowlse_fix<<<dim3(N_ROWS), dim3(256), 0, stream>>>(psum, ftl, lossi);
    k_final<<<dim3(1), dim3(512), 0, stream>>>(lossi, out);
}